// Round 2
// baseline (302.138 us; speedup 1.0000x reference)
//
#include <hip/hip_runtime.h>

#define TLEN 512
#define HID  64

typedef _Float16 half8 __attribute__((ext_vector_type(8)));
typedef float    f32x4 __attribute__((ext_vector_type(4)));

__device__ __forceinline__ float rcp_fast(float x) { return __builtin_amdgcn_rcpf(x); }
__device__ __forceinline__ float exp2_fast(float x) {
#if __has_builtin(__builtin_amdgcn_exp2f)
    return __builtin_amdgcn_exp2f(x);
#else
    float r; asm("v_exp_f32 %0, %1" : "=v"(r) : "v"(x)); return r;
#endif
}

// R13: 1-wave-per-SIMD attack. Evidence (R11 vs R12): step time ~= chain
// latency + (waves/SIMD - 1) x serialized issue; co-resident waves NEVER
// filled the barrier dead time (same phase or additive issue), they only
// added ~240 cyc/step of serialized VALU/trans/MFMA.
// Shape: 256 blocks x 256 thr (4 waves, 1 block/CU, 1 wave/SIMD). Wave owns
// 16 units as 4 A-tiles; lane does TWO activations (tiles dup and dup+2 ->
// uB = uA + 8): two independent c-chains give intra-wave ILP that fills the
// chain stalls instead of a sibling wave. Total MFMA work and trans-op count
// per CU-step unchanged vs R11; zero duplicated acts or writes.
// All per-step LDS addressing = 4 precomputed base pointers + imm offsets.
__global__ __launch_bounds__(256) __attribute__((amdgpu_waves_per_eu(1, 1)))
void lstm_w1(const float* __restrict__ x,
             const float* __restrict__ W_ih,
             const float* __restrict__ W_hh,
             const float* __restrict__ b_ih,
             const float* __restrict__ b_hh,
             const float* __restrict__ W_d,
             const float* __restrict__ b_d,
             float* __restrict__ out) {
    __shared__ __align__(16) float    xs[8][516];     // 8 x rows
    __shared__ __align__(16) _Float16 hbuf[2][8][80]; // ping-pong h

    const int tid = threadIdx.x;
    const int L   = tid & 63;
    const int w   = tid >> 6;        // wave 0..3, owns units [16w, 16w+16)
    const int r0  = blockIdx.x * 8;

    // ---- stage x rows (float4) ----
    for (int i = tid; i < 8 * 128; i += 256) {
        const int r = i >> 7, t4 = (i & 127) * 4;
        *(float4*)&xs[r][t4] = *(const float4*)&x[(size_t)(r0 + r) * TLEN + t4];
    }
    // ---- zero both h buffers (h0 = 0) ----
    for (int i = tid; i < 2 * 8 * 80; i += 256)
        ((_Float16*)hbuf)[i] = (_Float16)0.0f;

    // ---- resident A-frags: A[m][k], m=L&15, k=32q+(L>>4)*8+i ----
    // tile tt -> unit 16w+4tt+(m>>2), gate m&3 (i,f,g,o)
    half8 af[4][2];
    {
        const int m  = L & 15;
        const int g  = m & 3;
        const int kb = (L >> 4) * 8;
#pragma unroll
        for (int tt = 0; tt < 4; ++tt) {
            const int uu = 16 * w + 4 * tt + (m >> 2);
            const float* row = &W_hh[(size_t)(g * HID + uu) * HID];
#pragma unroll
            for (int q = 0; q < 2; ++q) {
                const float* p = row + 32 * q + kb;
                half8 hf;
#pragma unroll
                for (int i = 0; i < 8; ++i) hf[i] = (_Float16)p[i];
                af[tt][q] = hf;
            }
        }
    }

    // ---- lane role: col c, batch b (8 real rows), dup bit, TWO units ----
    const int c   = L & 15;
    const int b   = c & 7;
    const int dup = c >> 3;          // selects tile within pair
    const int rg  = L >> 4;
    const int uA  = 16 * w + 4 * dup + rg;   // from tile dup   (0/1)
    const int uB  = uA + 8;                  // from tile dup+2 (2/3)
    const bool d1 = dup != 0;
    // 64 lanes x 2 acts <-> 128 distinct (b,u): exactly 2 acts/lane, no dup.

    // exp2-domain gate params: sigmoid arg -K*a, tanh arg +2K*a (K=log2 e)
    const float K = 1.44269504f;
    float wihA[4], biasA[4], wihB[4], biasB[4], dscl[4];
#pragma unroll
    for (int g = 0; g < 4; ++g) {
        const float s = (g == 2) ? 2.0f * K : -K;
        wihA[g]  = s * W_ih[g * HID + uA];
        biasA[g] = s * (b_ih[g * HID + uA] + b_hh[g * HID + uA]);
        wihB[g]  = s * W_ih[g * HID + uB];
        biasB[g] = s * (b_ih[g * HID + uB] + b_hh[g * HID + uB]);
        dscl[g]  = s;
    }

    const float* xrow = &xs[b][0];
    const int koff = rg * 8;
    // 4 held base pointers; all steady-state LDS ops use them + imm offsets
    const _Float16* rd0 = &hbuf[0][b][koff];
    const _Float16* rd1 = &hbuf[1][b][koff];
    _Float16*       wr0 = &hbuf[0][0][b * 80 + uA];  // act B at +8 (16 B)
    _Float16*       wr1 = &hbuf[1][0][b * 80 + uA];
    const f32x4 zero = {0.0f, 0.0f, 0.0f, 0.0f};
    float cA = 0.0f, cB = 0.0f;

    __syncthreads();

    auto step = [&](const _Float16* rd, _Float16* wr, float xt) {
        // pre-gates for both acts: ready before MFMA results are consumed
        float preA[4], preB[4];
#pragma unroll
        for (int g = 0; g < 4; ++g) {
            preA[g] = fmaf(xt, wihA[g], biasA[g]);
            preB[g] = fmaf(xt, wihB[g], biasB[g]);
        }

        half8 b0 = *(const half8*)(rd);
        half8 b1 = *(const half8*)(rd + 32);

        // K-split partials: 8 independent MFMAs (no acc chaining)
        f32x4 p0 = __builtin_amdgcn_mfma_f32_16x16x32_f16(af[0][0], b0, zero, 0, 0, 0);
        f32x4 p1 = __builtin_amdgcn_mfma_f32_16x16x32_f16(af[1][0], b0, zero, 0, 0, 0);
        f32x4 p2 = __builtin_amdgcn_mfma_f32_16x16x32_f16(af[2][0], b0, zero, 0, 0, 0);
        f32x4 p3 = __builtin_amdgcn_mfma_f32_16x16x32_f16(af[3][0], b0, zero, 0, 0, 0);
        f32x4 q0 = __builtin_amdgcn_mfma_f32_16x16x32_f16(af[0][1], b1, zero, 0, 0, 0);
        f32x4 q1 = __builtin_amdgcn_mfma_f32_16x16x32_f16(af[1][1], b1, zero, 0, 0, 0);
        f32x4 q2 = __builtin_amdgcn_mfma_f32_16x16x32_f16(af[2][1], b1, zero, 0, 0, 0);
        f32x4 q3 = __builtin_amdgcn_mfma_f32_16x16x32_f16(af[3][1], b1, zero, 0, 0, 0);

        const f32x4 dPA = d1 ? p1 : p0;
        const f32x4 dQA = d1 ? q1 : q0;
        const f32x4 dPB = d1 ? p3 : p2;
        const f32x4 dQB = d1 ? q3 : q2;

        // ---- act A (unit uA) ----
        const float eiA = exp2_fast(fmaf(dPA[0] + dQA[0], dscl[0], preA[0]));
        const float efA = exp2_fast(fmaf(dPA[1] + dQA[1], dscl[1], preA[1]));
        const float egA = exp2_fast(fmaf(dPA[2] + dQA[2], dscl[2], preA[2]));
        const float eoA = exp2_fast(fmaf(dPA[3] + dQA[3], dscl[3], preA[3]));
        // ---- act B (unit uB) ---- independent chain, interleaves with A
        const float eiB = exp2_fast(fmaf(dPB[0] + dQB[0], dscl[0], preB[0]));
        const float efB = exp2_fast(fmaf(dPB[1] + dQB[1], dscl[1], preB[1]));
        const float egB = exp2_fast(fmaf(dPB[2] + dQB[2], dscl[2], preB[2]));
        const float eoB = exp2_fast(fmaf(dPB[3] + dQB[3], dscl[3], preB[3]));

        const float giA = rcp_fast(1.0f + eiA);
        const float gfA = rcp_fast(1.0f + efA);
        const float ggA = fmaf(-2.0f, rcp_fast(1.0f + egA), 1.0f);
        const float goA = rcp_fast(1.0f + eoA);
        const float giB = rcp_fast(1.0f + eiB);
        const float gfB = rcp_fast(1.0f + efB);
        const float ggB = fmaf(-2.0f, rcp_fast(1.0f + egB), 1.0f);
        const float goB = rcp_fast(1.0f + eoB);

        cA = fmaf(gfA, cA, giA * ggA);
        cB = fmaf(gfB, cB, giB * ggB);
        const float tcA = fmaf(-2.0f, rcp_fast(1.0f + exp2_fast(2.0f * K * cA)), 1.0f);
        const float tcB = fmaf(-2.0f, rcp_fast(1.0f + exp2_fast(2.0f * K * cB)), 1.0f);
        wr[0] = (_Float16)(goA * tcA);   // unit uA
        wr[8] = (_Float16)(goB * tcB);   // unit uB (imm offset 16 B)
    };

    for (int t = 0; t < TLEN; t += 4) {
        // x register-blocking: one b128 read covers 4 steps (16B-aligned)
        const float4 xq = *(const float4*)&xrow[t];
        step(rd0, wr1, xq.x);
        __syncthreads();
        step(rd1, wr0, xq.y);
        __syncthreads();
        step(rd0, wr1, xq.z);
        __syncthreads();
        step(rd1, wr0, xq.w);
        __syncthreads();
    }

    // ---- epilogue: wave w reduces batch rows w and w+4 (final h in hbuf[0]) ----
#pragma unroll
    for (int rr = w; rr < 8; rr += 4) {
        float pv = (float)hbuf[0][rr][L] * W_d[L];
#pragma unroll
        for (int off = 32; off > 0; off >>= 1)
            pv += __shfl_xor(pv, off, 64);
        if (L == 0)
            out[r0 + rr] = pv + b_d[0];
    }
}

extern "C" void kernel_launch(void* const* d_in, const int* in_sizes, int n_in,
                              void* d_out, int out_size, void* d_ws, size_t ws_size,
                              hipStream_t stream) {
    const float* x    = (const float*)d_in[0];
    const float* W_ih = (const float*)d_in[1];
    const float* W_hh = (const float*)d_in[2];
    const float* b_ih = (const float*)d_in[3];
    const float* b_hh = (const float*)d_in[4];
    const float* W_d  = (const float*)d_in[5];
    const float* b_d  = (const float*)d_in[6];
    float* out = (float*)d_out;

    dim3 grid(256);    // 2048 / 8 batch rows per block -> 1 block/CU
    dim3 block(256);   // 4 waves = 1 wave/SIMD: no sibling-issue tax
    lstm_w1<<<grid, block, 0, stream>>>(x, W_ih, W_hh, b_ih, b_hh, W_d, b_d, out);
}

// Round 3
// 203.958 us; speedup vs baseline: 1.4814x; 1.4814x over previous
//
#include <hip/hip_runtime.h>

#define TLEN 512
#define HID  64

typedef _Float16 half8 __attribute__((ext_vector_type(8)));
typedef float    f32x4 __attribute__((ext_vector_type(4)));

__device__ __forceinline__ float rcp_fast(float x) { return __builtin_amdgcn_rcpf(x); }
__device__ __forceinline__ float exp2_fast(float x) {
#if __has_builtin(__builtin_amdgcn_exp2f)
    return __builtin_amdgcn_exp2f(x);
#else
    float r; asm("v_exp_f32 %0, %1" : "=v"(r) : "v"(x)); return r;
#endif
}

// R14: trans-count attack on the R11 shape (best measured: 175 us).
// Model from R11/R12/R13: step = fixed issue (~485 VALU + 138 MFMA per
// SIMD-step) + ~200 dead; act bundle = 242 cyc of which 10 trans x 16 = 160.
// Cuts (algebraic, exact):
//  1. gi*gg = (eg-1)/[(1+ei)(1+eg)]           -- kills 1 rcp
//  2. c'   = [c*Pig + (eg-1)(1+ef)] / ((1+ef)*Pig)  -- kills gf's rcp
//  3. go*tanh(c') = (ec-1)/[(1+eo)(1+ec)]     -- kills 1 rcp
//  -> 5 exp2 + 2 rcp = 7 trans (was 10): -48 cyc/bundle.
//  4. exp2-domain scales (-K, +2K) folded into f16 A-matrix and wih/bias:
//     kills the 4 dscl-fmas; args become plain 3-way adds.
//  5. hbuf stride 72 -> 80: R11's 8.4M bank conflicts -> ~0 (R12/R13 data).
__global__ __launch_bounds__(512) __attribute__((amdgpu_waves_per_eu(2, 2)))
void lstm_mfma8(const float* __restrict__ x,
                const float* __restrict__ W_ih,
                const float* __restrict__ W_hh,
                const float* __restrict__ b_ih,
                const float* __restrict__ b_hh,
                const float* __restrict__ W_d,
                const float* __restrict__ b_d,
                float* __restrict__ out) {
    __shared__ __align__(16) float    xs[8][516];     // 8 x rows
    __shared__ __align__(16) _Float16 hbuf[2][8][80]; // ping-pong h, pad 80

    const int tid = threadIdx.x;
    const int L   = tid & 63;
    const int w   = tid >> 6;        // wave 0..7, owns units [8w, 8w+8)
    const int r0  = blockIdx.x * 8;

    // ---- stage x rows (float4) ----
    for (int i = tid; i < 8 * 128; i += 512) {
        const int r = i >> 7, t4 = (i & 127) * 4;
        *(float4*)&xs[r][t4] = *(const float4*)&x[(size_t)(r0 + r) * TLEN + t4];
    }
    // ---- zero both h buffers (h0 = 0) ----
    for (int i = tid; i < 2 * 8 * 80; i += 512)
        ((_Float16*)hbuf)[i] = (_Float16)0.0f;

    const float K = 1.44269504f;     // log2 e

    // ---- resident A-frags: A[m][k], m=L&15, k=32q+(L>>4)*8+i ----
    // perm: tile tt -> unit 8w+4tt+(m>>2), gate m&3 (i,f,g,o)
    // Gate scale folded into A: s = -K (i,f,o), +2K (g).
    half8 af[2][2];
    {
        const int m = L & 15;
        const int g = m & 3;
        const int kb = (L >> 4) * 8;
        const float sg = (g == 2) ? 2.0f * K : -K;
#pragma unroll
        for (int tt = 0; tt < 2; ++tt) {
            const int uu = 8 * w + 4 * tt + (m >> 2);
            const float* row = &W_hh[(size_t)(g * HID + uu) * HID];
#pragma unroll
            for (int q = 0; q < 2; ++q) {
                const float* p = row + 32 * q + kb;
                half8 hf;
#pragma unroll
                for (int i = 0; i < 8; ++i) hf[i] = (_Float16)(sg * p[i]);
                af[tt][q] = hf;
            }
        }
    }

    // ---- lane role: col c, batch b (8 real rows), tile-select dup, unit u ----
    const int c   = L & 15;
    const int b   = c & 7;
    const int dup = (c >> 3) & 1;
    const int u   = 8 * w + 4 * dup + (L >> 4);
    // 64 lanes <-> 64 distinct (b,u): exactly one activation per lane.

    // wih/bias pre-scaled into exp2 domain (same s as A rows)
    float wih[4], bias[4];
#pragma unroll
    for (int g = 0; g < 4; ++g) {
        const float s = (g == 2) ? 2.0f * K : -K;
        wih[g]  = s * W_ih[g * HID + u];
        bias[g] = s * (b_ih[g * HID + u] + b_hh[g * HID + u]);
    }
    const float K2 = 2.0f * K;

    const float* xrow = &xs[b][0];
    const int koff = (L >> 4) * 8;
    const _Float16* h0r = &hbuf[0][b][0];
    _Float16*       h0w = &hbuf[0][0][0];
    const _Float16* h1r = &hbuf[1][b][0];
    _Float16*       h1w = &hbuf[1][0][0];
    const int widx = b * 80 + u;     // write offset within a buffer
    const f32x4 zero = {0.0f, 0.0f, 0.0f, 0.0f};
    float cst = 0.0f;

    __syncthreads();

    auto step = [&](const _Float16* hin, _Float16* hout, float xt) {
        // pre-gates: ready before MFMA results are consumed
        const float pre0 = fmaf(xt, wih[0], bias[0]);
        const float pre1 = fmaf(xt, wih[1], bias[1]);
        const float pre2 = fmaf(xt, wih[2], bias[2]);
        const float pre3 = fmaf(xt, wih[3], bias[3]);

        half8 b0 = *(const half8*)(hin + koff);
        half8 b1 = *(const half8*)(hin + koff + 32);

        // K-split partials: 4 independent MFMAs (no acc chaining)
        f32x4 p0 = __builtin_amdgcn_mfma_f32_16x16x32_f16(af[0][0], b0, zero, 0, 0, 0);
        f32x4 p1 = __builtin_amdgcn_mfma_f32_16x16x32_f16(af[1][0], b0, zero, 0, 0, 0);
        f32x4 q0 = __builtin_amdgcn_mfma_f32_16x16x32_f16(af[0][1], b1, zero, 0, 0, 0);
        f32x4 q1 = __builtin_amdgcn_mfma_f32_16x16x32_f16(af[1][1], b1, zero, 0, 0, 0);

        const f32x4 dP = dup ? p1 : p0;   // 4 cndmask each
        const f32x4 dQ = dup ? q1 : q0;

        // args already scaled: -K*a for i,f,o; +2K*a for g
        const float ei = exp2_fast(dP[0] + dQ[0] + pre0);
        const float ef = exp2_fast(dP[1] + dQ[1] + pre1);
        const float eg = exp2_fast(dP[2] + dQ[2] + pre2);
        const float eo = exp2_fast(dP[3] + dQ[3] + pre3);

        // merged-ratio LSTM cell: 2 rcp total
        const float A1 = 1.0f + ei;
        const float B1 = 1.0f + eg;
        const float E1 = 1.0f + ef;
        const float C1 = eg - 1.0f;
        const float Pig = A1 * B1;               // (1+ei)(1+eg)
        const float Dde = E1 * Pig;              // common denominator
        const float num = fmaf(cst, Pig, C1 * E1);
        cst = num * rcp_fast(Dde);               // c' = gf*c + gi*gg
        const float ec = exp2_fast(K2 * cst);
        const float F1 = 1.0f + eo;
        const float G1 = 1.0f + ec;
        const float H1 = ec - 1.0f;
        const float hv = H1 * rcp_fast(F1 * G1); // go * tanh(c')
        hout[widx] = (_Float16)hv;  // one write per lane, 64 unique (b,u)
    };

    for (int t = 0; t < TLEN; t += 4) {
        // x register-blocking: one b128 read covers 4 steps (16B-aligned)
        const float4 xq = *(const float4*)&xrow[t];
        step(h0r, h1w, xq.x);
        __syncthreads();
        step(h1r, h0w, xq.y);
        __syncthreads();
        step(h0r, h1w, xq.z);
        __syncthreads();
        step(h1r, h0w, xq.w);
        __syncthreads();
    }

    // ---- epilogue: wave w reduces batch row w (final h in hbuf[0]) ----
    float pv = (float)hbuf[0][w][L] * W_d[L];
#pragma unroll
    for (int off = 32; off > 0; off >>= 1)
        pv += __shfl_xor(pv, off, 64);
    if (L == 0)
        out[r0 + w] = pv + b_d[0];
}

extern "C" void kernel_launch(void* const* d_in, const int* in_sizes, int n_in,
                              void* d_out, int out_size, void* d_ws, size_t ws_size,
                              hipStream_t stream) {
    const float* x    = (const float*)d_in[0];
    const float* W_ih = (const float*)d_in[1];
    const float* W_hh = (const float*)d_in[2];
    const float* b_ih = (const float*)d_in[3];
    const float* b_hh = (const float*)d_in[4];
    const float* W_d  = (const float*)d_in[5];
    const float* b_d  = (const float*)d_in[6];
    float* out = (float*)d_out;

    dim3 grid(256);    // 2048 / 8 batch rows per block -> 1 block/CU
    dim3 block(512);   // 8 waves = 2/SIMD (R11 shape, best measured)
    lstm_mfma8<<<grid, block, 0, stream>>>(x, W_ih, W_hh, b_ih, b_hh, W_d, b_d, out);
}